// Round 2
// baseline (253.041 us; speedup 1.0000x reference)
//
#include <hip/hip_runtime.h>
#include <stdint.h>

typedef unsigned short u16;
typedef __attribute__((ext_vector_type(8))) __bf16 bf16x8;
typedef __attribute__((ext_vector_type(4))) float f32x4;

__device__ __forceinline__ u16 f2bf(float f) {
  unsigned u = __float_as_uint(f);
  u += 0x7FFF + ((u >> 16) & 1);   // RNE
  return (u16)(u >> 16);
}

__device__ __forceinline__ float bf2f(u16 h) {
  return __uint_as_float(((unsigned)h) << 16);
}

__device__ __forceinline__ void llds16(const u16* g, u16* l) {
  __builtin_amdgcn_global_load_lds(
      (const __attribute__((address_space(1))) void*)g,
      (__attribute__((address_space(3))) void*)l, 16, 0, 0);
}

// ---------------------------------------------------------------------------
// fused cast fp32 -> bf16 for x | wq | wk | wv + zero the lsum accumulator
// ---------------------------------------------------------------------------
__global__ __launch_bounds__(256) void cast_all(
    const float* __restrict__ x, const float* __restrict__ wq,
    const float* __restrict__ wk, const float* __restrict__ wv,
    u16* __restrict__ xb, u16* __restrict__ wb, float* __restrict__ lsum) {
  int i = blockIdx.x * 256 + threadIdx.x;
  if (i < 8192) lsum[i] = 0.f;        // softmax-denominator accumulator
  const float* src; u16* dst; int off;
  if (i < 2097152)      { src = x;  dst = xb;            off = i; }
  else if (i < 2359296) { src = wq; dst = wb;            off = i - 2097152; }
  else if (i < 2621440) { src = wk; dst = wb + 1048576;  off = i - 2359296; }
  else                  { src = wv; dst = wb + 2097152;  off = i - 2621440; }
  float4 f = ((const float4*)src)[off];
  ushort4 o;
  o.x = f2bf(f.x); o.y = f2bf(f.y); o.z = f2bf(f.z); o.w = f2bf(f.w);
  ((ushort4*)dst)[off] = o;
}

// ---------------------------------------------------------------------------
// QKV projection: 256x256-tile, BK=64, 8-phase deep-pipelined GEMM (T1-T5)
//   C[8192,3072] = xb[8192,1024] @ wb[3072,1024]^T, cols<2048 -> qk bf16,
//   cols>=2048 -> vt transposed.
// Round-2 changes vs round-1 (which ran 73.7us, MfmaUtil 27, VALUBusy 12.5):
//   * stripped PH to the m201 skeleton: ONLY one sched_barrier(0), placed
//     after lgkmcnt(0) (rule #18).  Round-1 had 4 sched_barrier + memory
//     clobbers per phase -> m141-style order-pinning collapse.
//   * XCD-aware 1D-grid swizzle (384%8==0): s=(bid&7)*48+(bid>>3),
//     ct = s>>5 (each XCD's 48 blocks share 2 B-panels in its L2).
// Structure (guide §5 "256² 8-phase template"):
//   512 thr = 8 waves (2Mx4N), wave tile 128x64, acc[8][4] f32x4.
//   LDS 128KB: As/Bs[2 buf][2 khalf][128 rowpair][8 slot][8 u16].
//   Swizzle: content chunk cc = slot ^ (rowpair&7); row = 2j+(cc>>2),
//   k = kh*32 + (cc&3)*8.  Staged via pre-swizzled GLOBAL src + linear
//   global_load_lds dst (both-sides-or-neither, rule #21).  Frag read:
//   j = r>>1, slot = (((r&1)<<2)|chunk) ^ (j&7)  ->  2 lanes/slot = free.
// Schedule per K-tile (4 phases = ks x mhalf), 1 half-tile staged per phase,
// counted vmcnt(8) twice per K-tile (4 half-tiles = 8 loads stay in flight;
// never drains to 0 in the main loop); tail peeled vmcnt 8 -> 4 -> 0.
// ---------------------------------------------------------------------------
#define VM8 asm volatile("s_waitcnt vmcnt(8)" ::: "memory")
#define VM4 asm volatile("s_waitcnt vmcnt(4)" ::: "memory")
#define VM0 asm volatile("s_waitcnt vmcnt(0)" ::: "memory")
#define VMN ((void)0)

#define STGA(P, KH, KOFF) do {                                              \
  llds16(gA + (KOFF),          As + (P)*16384 + (KH)*8192 + t*8);           \
  llds16(gA + (KOFF) + 131072, As + (P)*16384 + (KH)*8192 + 4096 + t*8);    \
} while (0)

#define STGB(P, KH, KOFF) do {                                              \
  llds16(gB + (KOFF),          Bs + (P)*16384 + (KH)*8192 + t*8);           \
  llds16(gB + (KOFF) + 131072, Bs + (P)*16384 + (KH)*8192 + 4096 + t*8);    \
} while (0)

#define PH(P, KH, MH, RDB, VMW, ...) do {                                   \
  bf16x8 af[4];                                                             \
  { const int ab_ = (P)*16384 + (KH)*8192 + (wr*64 + (MH)*32)*64 + fr_off;  \
    af[0] = *(const bf16x8*)(As + ab_);                                     \
    af[1] = *(const bf16x8*)(As + ab_ + 512);                               \
    af[2] = *(const bf16x8*)(As + ab_ + 1024);                              \
    af[3] = *(const bf16x8*)(As + ab_ + 1536); }                            \
  if (RDB) {                                                                \
    const int bb_ = (P)*16384 + (KH)*8192 + (wc*32)*64 + fr_off;            \
    bfv[0] = *(const bf16x8*)(Bs + bb_);                                    \
    bfv[1] = *(const bf16x8*)(Bs + bb_ + 512);                              \
    bfv[2] = *(const bf16x8*)(Bs + bb_ + 1024);                             \
    bfv[3] = *(const bf16x8*)(Bs + bb_ + 1536); }                           \
  __VA_ARGS__;                                                              \
  __builtin_amdgcn_s_barrier();                                             \
  asm volatile("s_waitcnt lgkmcnt(0)" ::: "memory");                        \
  __builtin_amdgcn_sched_barrier(0);                                        \
  __builtin_amdgcn_s_setprio(1);                                            \
  _Pragma("unroll")                                                         \
  for (int m_ = 0; m_ < 4; ++m_) {                                          \
    _Pragma("unroll")                                                       \
    for (int n_ = 0; n_ < 4; ++n_)                                          \
      acc[(MH)*4 + m_][n_] = __builtin_amdgcn_mfma_f32_16x16x32_bf16(       \
          af[m_], bfv[n_], acc[(MH)*4 + m_][n_], 0, 0, 0);                  \
  }                                                                         \
  __builtin_amdgcn_s_setprio(0);                                            \
  VMW;                                                                      \
  __builtin_amdgcn_s_barrier();                                             \
} while (0)

__global__ __launch_bounds__(512, 2) void gemm_qkv(
    const u16* __restrict__ A, const u16* __restrict__ B,
    u16* __restrict__ qk, u16* __restrict__ vt) {
  __shared__ u16 As[32768];
  __shared__ u16 Bs[32768];
  const int t = threadIdx.x;
  const int lane = t & 63;
  const int wr = (t >> 6) >> 2;          // wave row 0..1   (128 rows each)
  const int wc = (t >> 6) & 3;           // wave col 0..3   (64 cols each)
  const int lr = lane & 15;
  const int q  = lane >> 4;
  // frag-read per-lane offset: rowpair low bits + swizzled slot
  const int fr_off = (lr >> 1) * 64 + ((((lr & 1) << 2) | q) ^ (lr >> 1)) * 8;

  // XCD-aware bijective swizzle (384 blocks, 384%8==0): each XCD gets 48
  // consecutive s; ct-major decode -> 2 B-panels (~1MB) reused per XCD-L2.
  const int s = (blockIdx.x & 7) * 48 + (blockIdx.x >> 3);
  const int ct = s >> 5;                 // 0..11
  const int rt = s & 31;                 // 0..31
  const int rowbase = rt << 8;
  const int colbase = ct << 8;

  // staging: thread t covers rowpair (t>>3), slot (t&7); content chunk
  // cc = slot ^ (rowpair&7) -> global row = base + 2*(t>>3) + (cc>>2),
  // global k-chunk = (cc&3).  Second call (+131072 = 128 rows) covers
  // rows 128..255.
  const int cc = (t & 7) ^ ((t >> 3) & 7);
  const u16* gA = A + (long long)(rowbase + ((t >> 3) << 1) + (cc >> 2)) * 1024
                    + (cc & 3) * 8;
  const u16* gB = B + (long long)(colbase + ((t >> 3) << 1) + (cc >> 2)) * 1024
                    + (cc & 3) * 8;

  f32x4 acc[8][4];
  const f32x4 z = {0.f, 0.f, 0.f, 0.f};
#pragma unroll
  for (int i = 0; i < 8; ++i)
#pragma unroll
    for (int j = 0; j < 4; ++j) acc[i][j] = z;
  bf16x8 bfv[4];

  // prologue: tile0 kh0, kh1 and tile1 kh0 (6 half-tiles = 12 loads/wave);
  // vmcnt(8) -> tile0-kh0 (A,B) guaranteed resident after barrier
  STGA(0, 0, 0);  STGB(0, 0, 0);
  STGA(0, 1, 32); STGB(0, 1, 32);
  STGA(1, 0, 64); STGB(1, 0, 64);
  VM8;
  __builtin_amdgcn_s_barrier();

#pragma unroll 1
  for (int tt = 0; tt < 7; ++tt) {          // tiles 0..13 (2 per iter)
    const int ka = tt * 128;                // k base (u16) of even tile
    // tile 2tt   (buf 0)
    PH(0, 0, 0, 1, VMN, STGA(1, 1, ka + 96));
    PH(0, 0, 1, 0, VM8, STGB(1, 1, ka + 96));
    PH(0, 1, 0, 1, VMN, STGA(0, 0, ka + 128));
    PH(0, 1, 1, 0, VM8, STGB(0, 0, ka + 128));
    // tile 2tt+1 (buf 1)
    PH(1, 0, 0, 1, VMN, STGA(0, 1, ka + 160));
    PH(1, 0, 1, 0, VM8, STGB(0, 1, ka + 160));
    PH(1, 1, 0, 1, VMN, STGA(1, 0, ka + 192));
    PH(1, 1, 1, 0, VM8, STGB(1, 0, ka + 192));
  }
  // tile 14 (buf 0): only kh1 of tile 15 remains to stage
  PH(0, 0, 0, 1, VMN, STGA(1, 1, 992));
  PH(0, 0, 1, 0, VM8, STGB(1, 1, 992));
  PH(0, 1, 0, 1, VMN);
  PH(0, 1, 1, 0, VM4);
  // tile 15 (buf 1)
  PH(1, 0, 0, 1, VMN);
  PH(1, 0, 1, 0, VM0);
  PH(1, 1, 0, 1, VMN);
  PH(1, 1, 1, 0, VMN);

  // ---- epilogue: C/D layout col=lane&15, row=(lane>>4)*4+reg (m89/m91) ----
  if (colbase >= 2048) {
    // V block: write transposed to vt[b][e][s]; 4 regs = 4 consecutive s
#pragma unroll
    for (int mi = 0; mi < 8; ++mi) {
      const int s0 = rowbase + wr * 128 + mi * 16 + q * 4;
      const int b = s0 >> 11, sl = s0 & 2047;
#pragma unroll
      for (int n = 0; n < 4; ++n) {
        const int e = colbase - 2048 + wc * 64 + n * 16 + lr;
        ushort4 o;
        o.x = f2bf(acc[mi][n][0]); o.y = f2bf(acc[mi][n][1]);
        o.z = f2bf(acc[mi][n][2]); o.w = f2bf(acc[mi][n][3]);
        *(ushort4*)(vt + ((long long)(b * 1024 + e)) * 2048 + sl) = o;
      }
    }
  } else {
#pragma unroll
    for (int mi = 0; mi < 8; ++mi) {
#pragma unroll
      for (int r = 0; r < 4; ++r) {
        const long long grow = rowbase + wr * 128 + mi * 16 + q * 4 + r;
#pragma unroll
        for (int n = 0; n < 4; ++n) {
          const int gcol = colbase + wc * 64 + n * 16 + lr;
          qk[grow * 2048 + gcol] = f2bf(acc[mi][n][r]);
        }
      }
    }
  }
}

#undef PH
#undef STGA
#undef STGB

// ---------------------------------------------------------------------------
// NT GEMM: C[M,N] = A[M,K] * B[N,K]^T   (row-major bf16, fp32 accum)
// 128x128 tile, BK=64, 256 threads = 4 waves (2x2), each wave 64x64 via 4x4
// mfma_f32_16x16x32_bf16, 2 k-steps/iter.  global_load_lds width-16 staging.
// LDS chunk-XOR swizzle: row r's 16B k-chunk c stored at slot c^(r&7) ->
// SQ_LDS_BANK_CONFLICT == 0 measured (round 5).  Do NOT switch to
// 32x32x16: its frag-read pattern re-conflicts under this swizzle
// (round 6: +4 cyc/ds_read_b128, QKV 65.4 -> 69.4 us).
// MODE 1: scores -> triangular decode, exp(s*scale) fused (|s|<~5.5, no
//         max-subtraction needed), causal -> 0, row-sums via atomicAdd
// MODE 2: PV -> fp32, * rcp(lsum[row]), causal K-truncation, longest-first
// ---------------------------------------------------------------------------
template<int MODE>
__global__ __launch_bounds__(256) void gemm_nt(
    const u16* __restrict__ A, long long sA, int lda,
    const u16* __restrict__ B, long long sB, int ldb,
    void* __restrict__ Cp, long long sC, int ldc,
    int K, u16* __restrict__ vt, float scale,
    float* __restrict__ lsum, const int* __restrict__ causalp) {
  const int t = threadIdx.x;
  const int causal = (MODE == 0) ? 1 : causalp[0];

  int rt = blockIdx.x, ct = blockIdx.y;
  if (MODE == 1) {
    // decode blockIdx.x (0..255) -> (rt, ct); first 136 = lower triangle,
    // last 120 = strict upper (skip instantly if causal)
    int x = blockIdx.x;
    if (x < 136) {
      int r = (int)((sqrtf(8.0f * x + 1.0f) - 1.0f) * 0.5f);
      while ((r + 1) * (r + 2) / 2 <= x) ++r;
      while (r * (r + 1) / 2 > x) --r;
      rt = r; ct = x - r * (r + 1) / 2;
    } else {
      int y = x - 136;
      int r = (int)((sqrtf(8.0f * y + 1.0f) - 1.0f) * 0.5f);
      while ((r + 1) * (r + 2) / 2 <= y) ++r;
      while (r * (r + 1) / 2 > y) --r;
      int c = y - r * (r + 1) / 2;
      rt = c; ct = r + 1;                   // strict upper tile
      if (causal) return;                   // never needed when causal
    }
  }
  if (MODE == 2) rt = 15 - blockIdx.x;      // longest K first

  const int rowbase = rt * 128;
  const int colbase = ct * 128;
  const u16* Ab = A + (long long)blockIdx.z * sA;
  const u16* Bb = B + (long long)blockIdx.z * sB;

  // causal PV: P[i,k]=0 for k>i -> only need k < rowbase+128
  int Keff = K;
  if (MODE == 2 && causal) Keff = min(K, rowbase + 128);

  __shared__ u16 As[8192];   // [128][64] u16, chunk-swizzled
  __shared__ u16 Bs[8192];

  const int lane = t & 63;
  const int wv = t >> 6;
  const int wr = wv >> 1;
  const int wc = wv & 1;
  const int quad = lane >> 4;
  const int lr = lane & 15;

  f32x4 acc[4][4];
  const f32x4 zero = {0.f, 0.f, 0.f, 0.f};
#pragma unroll
  for (int i = 0; i < 4; ++i)
#pragma unroll
    for (int j = 0; j < 4; ++j) acc[i][j] = zero;

  {
    // staging: load i covers rows i*32+(t>>3); lane fetches global chunk
    // (t&7)^((t>>3)&7) of its row (row&7 == (t>>3)&7 since i*32%8==0) so
    // the lane-linear DMA write produces the slot = chunk^(row&7) layout.
    const int csw = (t & 7) ^ ((t >> 3) & 7);
    const u16* ga = Ab + (long long)(rowbase + (t >> 3)) * lda + csw * 8;
    const u16* gb = Bb + (long long)(colbase + (t >> 3)) * ldb + csw * 8;
    const long long ra = 32LL * lda, rb = 32LL * ldb;
    u16* la = As + t * 8;
    u16* lb = Bs + t * 8;

    // frag read: row = wr*64 + tm*16 + lr, chunk = quad + ks*4,
    // slot = chunk ^ (lr&7)  (row&7 == lr&7);  ks=1 toggles u16-offset 32
    const int m7 = lr & 7;
    const int a_base = (wr * 64 + lr) * 64 + ((quad ^ m7) * 8);
    const int b_base = (wc * 64 + lr) * 64 + ((quad ^ m7) * 8);

    for (int k0 = 0; k0 < Keff; k0 += 64) {
      __syncthreads();               // prior frag reads done before overwrite
#pragma unroll
      for (int i = 0; i < 4; ++i) {
        llds16(ga + k0 + i * ra, la + i * 2048);
        llds16(gb + k0 + i * rb, lb + i * 2048);
      }
      __syncthreads();               // compiler drains vmcnt before barrier
#pragma unroll
      for (int ks = 0; ks < 2; ++ks) {
        const int ko = ks ? 32 : 0;  // slot ^= 4  ->  u16 offset ^ 32
        bf16x8 af[4], bfv[4];
#pragma unroll
        for (int tm = 0; tm < 4; ++tm)
          af[tm] = *(const bf16x8*)(As + ((a_base + tm * 1024) ^ ko));
#pragma unroll
        for (int tn = 0; tn < 4; ++tn)
          bfv[tn] = *(const bf16x8*)(Bs + ((b_base + tn * 1024) ^ ko));
#pragma unroll
        for (int tm = 0; tm < 4; ++tm)
#pragma unroll
          for (int tn = 0; tn < 4; ++tn)
            acc[tm][tn] = __builtin_amdgcn_mfma_f32_16x16x32_bf16(
                af[tm], bfv[tn], acc[tm][tn], 0, 0, 0);
      }
    }
  }

  // ------------------------------ epilogue ------------------------------
  // C/D layout (m89/m91): col = lane&15, row = (lane>>4)*4 + reg
  if (MODE == 0 && colbase >= 2048) {
    // V block: write transposed to vt[b][e][s]; 4 regs = 4 consecutive s
#pragma unroll
    for (int tm = 0; tm < 4; ++tm) {
      int s0 = rowbase + wr * 64 + tm * 16 + quad * 4;
      int b = s0 >> 11;
      int sl = s0 & 2047;
#pragma unroll
      for (int tn = 0; tn < 4; ++tn) {
        int e = colbase - 2048 + wc * 64 + tn * 16 + lr;
        ushort4 o;
        o.x = f2bf(acc[tm][tn][0]);
        o.y = f2bf(acc[tm][tn][1]);
        o.z = f2bf(acc[tm][tn][2]);
        o.w = f2bf(acc[tm][tn][3]);
        *(ushort4*)(vt + ((long long)(b * 1024 + e)) * 2048 + sl) = o;
      }
    }
    return;
  }

#pragma unroll
  for (int tm = 0; tm < 4; ++tm) {
#pragma unroll
    for (int r = 0; r < 4; ++r) {
      const int grow = rowbase + wr * 64 + tm * 16 + quad * 4 + r;
      float li, rsum = 0.f;
      if (MODE == 2) li = __builtin_amdgcn_rcpf(lsum[blockIdx.z * 2048 + grow]);
#pragma unroll
      for (int tn = 0; tn < 4; ++tn) {
        const int gcol = colbase + wc * 64 + tn * 16 + lr;
        float val = acc[tm][tn][r];
        if (MODE == 0) {
          ((u16*)Cp)[(long long)grow * ldc + gcol] = f2bf(val);
        } else if (MODE == 1) {
          u16* C = (u16*)Cp + (long long)blockIdx.z * sC;
          float ex = (causal && gcol > grow) ? 0.f : __expf(val * scale);
          C[(long long)grow * ldc + gcol] = f2bf(ex);
          rsum += ex;
        } else {
          float* C = (float*)Cp + (long long)blockIdx.z * sC;
          C[(long long)grow * ldc + gcol] = val * li;
        }
      }
      if (MODE == 1) {
        // reduce over the 16 col-lanes of this row (within the quad),
        // then one atomic per row-instance
#pragma unroll
        for (int o = 8; o > 0; o >>= 1) rsum += __shfl_xor(rsum, o, 64);
        if (lr == 0)
          atomicAdd(&lsum[blockIdx.z * 2048 + grow], rsum);
      }
    }
  }
}

// ---------------------------------------------------------------------------
extern "C" void kernel_launch(void* const* d_in, const int* in_sizes, int n_in,
                              void* d_out, int out_size, void* d_ws, size_t ws_size,
                              hipStream_t stream) {
  const float* x  = (const float*)d_in[0];
  const float* wq = (const float*)d_in[1];
  const float* wk = (const float*)d_in[2];
  const float* wv = (const float*)d_in[3];
  const int* causal = (const int*)d_in[4];
  float* out = (float*)d_out;

  // workspace layout (bytes):
  //   xb 0..16,777,216   wb ..23,068,672   qk ..56,623,104
  //   vt ..73,400,320    sb ..106,954,752  lsum ..106,987,520
  char* ws = (char*)d_ws;
  u16* xb = (u16*)(ws);               // [8192][1024] bf16 x
  u16* wb = (u16*)(ws + 16777216);    // [3072][1024] bf16 Wq|Wk|Wv
  u16* qk = (u16*)(ws + 23068672);    // [8192][2048] bf16 Q|K
  u16* vt = (u16*)(ws + 56623104);    // [4][1024][2048] bf16 V^T
  u16* sb = (u16*)(ws + 73400320);    // [4][2048][2048] bf16 exp-scores
  float* lsum = (float*)(ws + 106954752);  // [4][2048] softmax denominators

  // casts (x, wq, wk, wv -> bf16) + lsum zero-init, one launch
  cast_all<<<11264, 256, 0, stream>>>(x, wq, wk, wv, xb, wb, lsum);

  // QKV: [8192 x 3072] = xb @ wb^T ; Q,K -> qk, V -> vt (transposed)
  // 256x256-tile 8-phase pipelined kernel (384 blocks, XCD-swizzled, 512 thr)
  gemm_qkv<<<dim3(384, 1, 1), 512, 0, stream>>>(xb, wb, qk, vt);

  // exp-scores per batch: P' = exp((Q @ K^T)/32), causal -> 0, bf16;
  // row sums accumulate into lsum via atomics
  gemm_nt<1><<<dim3(256, 1, 4), 256, 0, stream>>>(
      qk, 2048LL * 2048, 2048, qk + 1024, 2048LL * 2048, 2048,
      sb, 2048LL * 2048, 2048, 1024, nullptr, 0.03125f, lsum, causal);

  // out per batch: [2048 x 1024] = (P' @ (V^T)^T) * rcp(lsum) -> fp32
  gemm_nt<2><<<dim3(16, 8, 4), 256, 0, stream>>>(
      sb, 2048LL * 2048, 2048, vt, 1024LL * 2048, 2048,
      out, 2048LL * 1024, 1024, 2048, nullptr, 1.0f, lsum, causal);
}

// Round 3
// 222.175 us; speedup vs baseline: 1.1389x; 1.1389x over previous
//
#include <hip/hip_runtime.h>
#include <stdint.h>

typedef unsigned short u16;
typedef __attribute__((ext_vector_type(8))) __bf16 bf16x8;
typedef __attribute__((ext_vector_type(4))) float f32x4;

__device__ __forceinline__ u16 f2bf(float f) {
  unsigned u = __float_as_uint(f);
  u += 0x7FFF + ((u >> 16) & 1);   // RNE
  return (u16)(u >> 16);
}

__device__ __forceinline__ float bf2f(u16 h) {
  return __uint_as_float(((unsigned)h) << 16);
}

__device__ __forceinline__ void llds16(const u16* g, u16* l) {
  __builtin_amdgcn_global_load_lds(
      (const __attribute__((address_space(1))) void*)g,
      (__attribute__((address_space(3))) void*)l, 16, 0, 0);
}

// ---------------------------------------------------------------------------
// fused cast fp32 -> bf16 for x | wq | wk | wv + zero the lsum accumulator
// ---------------------------------------------------------------------------
__global__ __launch_bounds__(256) void cast_all(
    const float* __restrict__ x, const float* __restrict__ wq,
    const float* __restrict__ wk, const float* __restrict__ wv,
    u16* __restrict__ xb, u16* __restrict__ wb, float* __restrict__ lsum) {
  int i = blockIdx.x * 256 + threadIdx.x;
  if (i < 8192) lsum[i] = 0.f;        // softmax-denominator accumulator
  const float* src; u16* dst; int off;
  if (i < 2097152)      { src = x;  dst = xb;            off = i; }
  else if (i < 2359296) { src = wq; dst = wb;            off = i - 2097152; }
  else if (i < 2621440) { src = wk; dst = wb + 1048576;  off = i - 2359296; }
  else                  { src = wv; dst = wb + 2097152;  off = i - 2621440; }
  float4 f = ((const float4*)src)[off];
  ushort4 o;
  o.x = f2bf(f.x); o.y = f2bf(f.y); o.z = f2bf(f.z); o.w = f2bf(f.w);
  ((ushort4*)dst)[off] = o;
}

// ---------------------------------------------------------------------------
// NT GEMM: C[M,N] = A[M,K] * B[N,K]^T   (row-major bf16, fp32 accum)
// 128x128 tile, BK=64, 256 threads = 4 waves (2x2), each wave 64x64 via 4x4
// mfma_f32_16x16x32_bf16, 2 k-steps/iter.  global_load_lds width-16 staging.
// LDS chunk-XOR swizzle: row r's 16B k-chunk c stored at slot c^(r&7) ->
// SQ_LDS_BANK_CONFLICT == 0 measured.  Do NOT switch to 32x32x16: its
// frag-read pattern re-conflicts under this swizzle.
// NOTE (rounds 1-2): a 256x256-tile 8-phase port of this GEMM ran SLOWER
// (626-700 TF vs 786 TF here): 1 block/CU -> 384-block grid quantizes to
// 2 rounds (75% util) and K=1024 is too short to amortize the pipeline.
// Keep the 128^2 structure for this problem shape.
// MODE 0: QKV  -> cols <2048 to qk (bf16), cols >=2048 to vt transposed
// MODE 1: scores -> XCD-chunked ct-major triangular decode (T1): XCD k owns
//         ct-major lower-tri indices [17k,17k+17) (136 = 8*17) so each XCD
//         reuses 1-2 K-panels (256KB, L2-resident); exp(s*scale) fused
//         (|s| small, no max-subtraction), causal -> 0, row-sums atomicAdd
// MODE 2: PV -> 1-D 512-block grid, XCD k owns 4 (batch,coltile) pairs
//         (2MB V^T panels L2-resident); fp32 out * rcp(lsum[row]); causal
//         K-truncation; longest-K-first within each XCD
// ---------------------------------------------------------------------------
template<int MODE>
__global__ __launch_bounds__(256) void gemm_nt(
    const u16* __restrict__ A, long long sA, int lda,
    const u16* __restrict__ B, long long sB, int ldb,
    void* __restrict__ Cp, long long sC, int ldc,
    int K, u16* __restrict__ vt, float scale,
    float* __restrict__ lsum, const int* __restrict__ causalp) {
  const int t = threadIdx.x;
  const int causal = (MODE == 0) ? 1 : causalp[0];

  int rt = blockIdx.x, ct = blockIdx.y, zb = blockIdx.z;
  if (MODE == 1) {
    // XCD-contiguous remap: xcd = x&7 (256%8==0 so z doesn't perturb),
    // chunk = x>>3 (0..31).  Working (lower-tri, 136=8*17): chunks 0..16
    // -> sx = xcd*17+chunk; leftovers (chunks 17..31, 15 each) -> strict
    // upper sx-136 = xcd*15+(chunk-17).  Lower decoded ct-MAJOR so one
    // XCD's 17 indices share 1-2 ct (K-panel L2 reuse).
    const int xcd = blockIdx.x & 7, chunk = blockIdx.x >> 3;
    if (chunk < 17) {
      int i2 = xcd * 17 + chunk, c = 0;
      while (i2 >= 16 - c) { i2 -= 16 - c; ++c; }
      ct = c; rt = c + i2;                  // ct-major lower triangle
    } else {
      if (causal) return;                   // strict upper: never needed
      int i2 = xcd * 15 + (chunk - 17), r = 0;
      while (i2 >= r + 1) { i2 -= r + 1; ++r; }
      rt = i2; ct = r + 1;                  // strict upper tile
    }
  }
  if (MODE == 2) {
    // 1-D grid of 512: xcd = bid&7 owns s in [64*xcd, 64*xcd+64) ->
    // batch zb = s>>7 fixed per XCD-pair, 4 coltiles (2MB V^T, L2-fit),
    // rt = 15-xx keeps longest-K-first.
    const int s = ((blockIdx.x & 7) << 6) + (blockIdx.x >> 3);
    zb = s >> 7;
    const int rem = s & 127;
    ct = rem >> 4;
    rt = 15 - (rem & 15);
  }

  const int rowbase = rt * 128;
  const int colbase = ct * 128;
  const u16* Ab = A + (long long)zb * sA;
  const u16* Bb = B + (long long)zb * sB;

  // causal PV: P[i,k]=0 for k>i -> only need k < rowbase+128
  int Keff = K;
  if (MODE == 2 && causal) Keff = min(K, rowbase + 128);

  __shared__ u16 As[8192];   // [128][64] u16, chunk-swizzled
  __shared__ u16 Bs[8192];

  const int lane = t & 63;
  const int wv = t >> 6;
  const int wr = wv >> 1;
  const int wc = wv & 1;
  const int quad = lane >> 4;
  const int lr = lane & 15;

  f32x4 acc[4][4];
  const f32x4 zero = {0.f, 0.f, 0.f, 0.f};
#pragma unroll
  for (int i = 0; i < 4; ++i)
#pragma unroll
    for (int j = 0; j < 4; ++j) acc[i][j] = zero;

  {
    // staging: load i covers rows i*32+(t>>3); lane fetches global chunk
    // (t&7)^((t>>3)&7) of its row (row&7 == (t>>3)&7 since i*32%8==0) so
    // the lane-linear DMA write produces the slot = chunk^(row&7) layout.
    const int csw = (t & 7) ^ ((t >> 3) & 7);
    const u16* ga = Ab + (long long)(rowbase + (t >> 3)) * lda + csw * 8;
    const u16* gb = Bb + (long long)(colbase + (t >> 3)) * ldb + csw * 8;
    const long long ra = 32LL * lda, rb = 32LL * ldb;
    u16* la = As + t * 8;
    u16* lb = Bs + t * 8;

    // frag read: row = wr*64 + tm*16 + lr, chunk = quad + ks*4,
    // slot = chunk ^ (lr&7)  (row&7 == lr&7);  ks=1 toggles u16-offset 32
    const int m7 = lr & 7;
    const int a_base = (wr * 64 + lr) * 64 + ((quad ^ m7) * 8);
    const int b_base = (wc * 64 + lr) * 64 + ((quad ^ m7) * 8);

    for (int k0 = 0; k0 < Keff; k0 += 64) {
      __syncthreads();               // prior frag reads done before overwrite
#pragma unroll
      for (int i = 0; i < 4; ++i) {
        llds16(ga + k0 + i * ra, la + i * 2048);
        llds16(gb + k0 + i * rb, lb + i * 2048);
      }
      __syncthreads();               // compiler drains vmcnt before barrier
#pragma unroll
      for (int ks = 0; ks < 2; ++ks) {
        const int ko = ks ? 32 : 0;  // slot ^= 4  ->  u16 offset ^ 32
        bf16x8 af[4], bfv[4];
#pragma unroll
        for (int tm = 0; tm < 4; ++tm)
          af[tm] = *(const bf16x8*)(As + ((a_base + tm * 1024) ^ ko));
#pragma unroll
        for (int tn = 0; tn < 4; ++tn)
          bfv[tn] = *(const bf16x8*)(Bs + ((b_base + tn * 1024) ^ ko));
#pragma unroll
        for (int tm = 0; tm < 4; ++tm)
#pragma unroll
          for (int tn = 0; tn < 4; ++tn)
            acc[tm][tn] = __builtin_amdgcn_mfma_f32_16x16x32_bf16(
                af[tm], bfv[tn], acc[tm][tn], 0, 0, 0);
      }
    }
  }

  // ------------------------------ epilogue ------------------------------
  // C/D layout (m89/m91): col = lane&15, row = (lane>>4)*4 + reg
  if (MODE == 0 && colbase >= 2048) {
    // V block: write transposed to vt[b][e][s]; 4 regs = 4 consecutive s
#pragma unroll
    for (int tm = 0; tm < 4; ++tm) {
      int s0 = rowbase + wr * 64 + tm * 16 + quad * 4;
      int b = s0 >> 11;
      int sl = s0 & 2047;
#pragma unroll
      for (int tn = 0; tn < 4; ++tn) {
        int e = colbase - 2048 + wc * 64 + tn * 16 + lr;
        ushort4 o;
        o.x = f2bf(acc[tm][tn][0]);
        o.y = f2bf(acc[tm][tn][1]);
        o.z = f2bf(acc[tm][tn][2]);
        o.w = f2bf(acc[tm][tn][3]);
        *(ushort4*)(vt + ((long long)(b * 1024 + e)) * 2048 + sl) = o;
      }
    }
    return;
  }

#pragma unroll
  for (int tm = 0; tm < 4; ++tm) {
#pragma unroll
    for (int r = 0; r < 4; ++r) {
      const int grow = rowbase + wr * 64 + tm * 16 + quad * 4 + r;
      float li, rsum = 0.f;
      if (MODE == 2) li = __builtin_amdgcn_rcpf(lsum[zb * 2048 + grow]);
#pragma unroll
      for (int tn = 0; tn < 4; ++tn) {
        const int gcol = colbase + wc * 64 + tn * 16 + lr;
        float val = acc[tm][tn][r];
        if (MODE == 0) {
          ((u16*)Cp)[(long long)grow * ldc + gcol] = f2bf(val);
        } else if (MODE == 1) {
          u16* C = (u16*)Cp + (long long)zb * sC;
          float ex = (causal && gcol > grow) ? 0.f : __expf(val * scale);
          C[(long long)grow * ldc + gcol] = f2bf(ex);
          rsum += ex;
        } else {
          float* C = (float*)Cp + (long long)zb * sC;
          C[(long long)grow * ldc + gcol] = val * li;
        }
      }
      if (MODE == 1) {
        // reduce over the 16 col-lanes of this row (within the quad),
        // then one atomic per row-instance
#pragma unroll
        for (int o = 8; o > 0; o >>= 1) rsum += __shfl_xor(rsum, o, 64);
        if (lr == 0)
          atomicAdd(&lsum[zb * 2048 + grow], rsum);
      }
    }
  }
}

// ---------------------------------------------------------------------------
extern "C" void kernel_launch(void* const* d_in, const int* in_sizes, int n_in,
                              void* d_out, int out_size, void* d_ws, size_t ws_size,
                              hipStream_t stream) {
  const float* x  = (const float*)d_in[0];
  const float* wq = (const float*)d_in[1];
  const float* wk = (const float*)d_in[2];
  const float* wv = (const float*)d_in[3];
  const int* causal = (const int*)d_in[4];
  float* out = (float*)d_out;

  // workspace layout (bytes):
  //   xb 0..16,777,216   wb ..23,068,672   qk ..56,623,104
  //   vt ..73,400,320    sb ..106,954,752  lsum ..106,987,520
  char* ws = (char*)d_ws;
  u16* xb = (u16*)(ws);               // [8192][1024] bf16 x
  u16* wb = (u16*)(ws + 16777216);    // [3072][1024] bf16 Wq|Wk|Wv
  u16* qk = (u16*)(ws + 23068672);    // [8192][2048] bf16 Q|K
  u16* vt = (u16*)(ws + 56623104);    // [4][1024][2048] bf16 V^T
  u16* sb = (u16*)(ws + 73400320);    // [4][2048][2048] bf16 exp-scores
  float* lsum = (float*)(ws + 106954752);  // [4][2048] softmax denominators

  // casts (x, wq, wk, wv -> bf16) + lsum zero-init, one launch
  cast_all<<<11264, 256, 0, stream>>>(x, wq, wk, wv, xb, wb, lsum);

  // QKV: [8192 x 3072] = xb @ wb^T ; Q,K -> qk, V -> vt (transposed)
  gemm_nt<0><<<dim3(64, 24, 1), 256, 0, stream>>>(
      xb, 0, 1024, wb, 0, 1024, qk, 0, 2048, 1024, vt, 1.0f, nullptr, causal);

  // exp-scores per batch: P' = exp((Q @ K^T)/32), causal -> 0, bf16;
  // row sums accumulate into lsum via atomics
  gemm_nt<1><<<dim3(256, 1, 4), 256, 0, stream>>>(
      qk, 2048LL * 2048, 2048, qk + 1024, 2048LL * 2048, 2048,
      sb, 2048LL * 2048, 2048, 1024, nullptr, 0.03125f, lsum, causal);

  // out per batch: [2048 x 1024] = (P' @ (V^T)^T) * rcp(lsum) -> fp32
  gemm_nt<2><<<dim3(512, 1, 1), 256, 0, stream>>>(
      sb, 2048LL * 2048, 2048, vt, 1024LL * 2048, 2048,
      out, 2048LL * 1024, 1024, 2048, nullptr, 1.0f, lsum, causal);
}